// Round 3
// baseline (169.429 us; speedup 1.0000x reference)
//
#include <hip/hip_runtime.h>
#include <stdint.h>

#define NXS 8192
#define HS  1024

typedef __attribute__((ext_vector_type(8))) short short8;
typedef __attribute__((ext_vector_type(4))) float f32x4;

__device__ __forceinline__ float bf2f(uint32_t b) {
    union { uint32_t u; float f; } c; c.u = b << 16; return c.f;
}
__device__ __forceinline__ uint16_t f2bf(float f) {
    union { float f; uint32_t u; } c; c.f = f;
    return (uint16_t)((c.u + 0x7fffu + ((c.u >> 16) & 1u)) >> 16);
}
__device__ __forceinline__ void async_cp16(const void* g, void* l) {
    __builtin_amdgcn_global_load_lds(
        (const __attribute__((address_space(1))) void*)g,
        (__attribute__((address_space(3))) void*)l,
        16, 0, 0);
}

// ---- K0: W2 (fp32) -> W2c (bf16 row-major) + W2T (bf16 transposed) ----
__global__ __launch_bounds__(256) void conv_w2(
    const float* __restrict__ W2, uint16_t* __restrict__ W2c,
    uint16_t* __restrict__ W2T)
{
    __shared__ uint16_t tile[64][65];
    const int bx = blockIdx.x & 15, by = blockIdx.x >> 4;
    const int tx = threadIdx.x & 63, ty = threadIdx.x >> 6;
#pragma unroll
    for (int rr = 0; rr < 64; rr += 4) {
        int r = ty + rr;
        uint16_t v = f2bf(W2[(size_t)(by * 64 + r) * HS + bx * 64 + tx]);
        W2c[(size_t)(by * 64 + r) * HS + bx * 64 + tx] = v;
        tile[r][tx] = v;
    }
    __syncthreads();
#pragma unroll
    for (int rr = 0; rr < 64; rr += 4)
        W2T[(size_t)(bx * 64 + ty + rr) * HS + by * 64 + tx] = tile[tx][ty + rr];
}

// ---- K1: Z1 = tanh(x @ W1^T + b1)  (fp32 in, bf16 out) ----
__global__ __launch_bounds__(256) void k1_z1(
    const float* __restrict__ x, const float* __restrict__ W1,
    const float* __restrict__ b1, uint16_t* __restrict__ Z1)
{
    const int idx = blockIdx.x * 256 + threadIdx.x;   // n*1024 + j
    const int n = idx >> 10, j = idx & 1023;
    float4 x0 = *(const float4*)(x + n * 8);
    float4 x1 = *(const float4*)(x + n * 8 + 4);
    float4 w0 = *(const float4*)(W1 + j * 8);
    float4 w1 = *(const float4*)(W1 + j * 8 + 4);
    float s = b1[j]
        + x0.x * w0.x + x0.y * w0.y + x0.z * w0.z + x0.w * w0.w
        + x1.x * w1.x + x1.y * w1.y + x1.z * w1.z + x1.w * w1.w;
    Z1[idx] = f2bf(tanhf(s));
}

// ---------------- GEMM (128x128 tile, mfma 16x16x32 bf16) ----------------
// MODE 0: C = A @ B^T (B row-major [N][K]); epilogue tanh -> V (bf16), y atomics
// MODE 1: plain bf16 store of C
template <int MODE>
__global__ __launch_bounds__(256) void gemm_k(
    const uint16_t* __restrict__ A, const uint16_t* __restrict__ B,
    const float* __restrict__ bias, const float* __restrict__ W3,
    uint16_t* __restrict__ Out, float* __restrict__ yacc)
{
    __shared__ __attribute__((aligned(16))) uint16_t lsA[128 * 32];
    __shared__ __attribute__((aligned(16))) uint16_t lsB[128 * 32];
    const int t = threadIdx.x;
    const int wave = t >> 6, lane = t & 63;
    const int lq = lane >> 4, lr = lane & 15;
    const int wm = wave >> 1, wn = wave & 1;
    const int rowBase = blockIdx.x * 128;
    const int colBase = blockIdx.y * 128;
    const int sRow = t >> 2, sCol = (t & 3) * 8;

    f32x4 acc[4][4] = {};

    for (int k0 = 0; k0 < HS; k0 += 32) {
#pragma unroll
        for (int i = 0; i < 2; ++i) {
            async_cp16(A + (size_t)(rowBase + i * 64 + sRow) * HS + k0 + sCol,
                       (char*)lsA + i * 4096 + wave * 1024);
            async_cp16(B + (size_t)(colBase + i * 64 + sRow) * HS + k0 + sCol,
                       (char*)lsB + i * 4096 + wave * 1024);
        }
        __syncthreads();
        short8 af[4], bfr[4];
#pragma unroll
        for (int ti = 0; ti < 4; ++ti)
            af[ti] = *(const short8*)((const short*)lsA + (wm * 64 + ti * 16 + lr) * 32 + lq * 8);
#pragma unroll
        for (int tj = 0; tj < 4; ++tj)
            bfr[tj] = *(const short8*)((const short*)lsB + (wn * 64 + tj * 16 + lr) * 32 + lq * 8);
#pragma unroll
        for (int ti = 0; ti < 4; ++ti)
#pragma unroll
            for (int tj = 0; tj < 4; ++tj)
                acc[ti][tj] = __builtin_amdgcn_mfma_f32_16x16x32_bf16(
                    af[ti], bfr[tj], acc[ti][tj], 0, 0, 0);
        __syncthreads();
    }

    if (MODE == 0) {
        float cB[4], cW[4]; int cCol[4];
#pragma unroll
        for (int tj = 0; tj < 4; ++tj) {
            int col = colBase + wn * 64 + tj * 16 + lr;
            cCol[tj] = col;
            cB[tj] = bias[col];
            cW[tj] = W3[col];
        }
#pragma unroll
        for (int ti = 0; ti < 4; ++ti) {
#pragma unroll
            for (int r = 0; r < 4; ++r) {
                int row = rowBase + wm * 64 + ti * 16 + lq * 4 + r;
                float ys = 0.f;
#pragma unroll
                for (int tj = 0; tj < 4; ++tj) {
                    float z2 = tanhf(acc[ti][tj][r] + cB[tj]);
                    ys += z2 * cW[tj];
                    Out[(size_t)row * HS + cCol[tj]] = f2bf((1.f - z2 * z2) * cW[tj]);
                }
                ys += __shfl_xor(ys, 1); ys += __shfl_xor(ys, 2);
                ys += __shfl_xor(ys, 4); ys += __shfl_xor(ys, 8);
                if (lr == 0) atomicAdd(&yacc[row], ys);
            }
        }
    } else {
#pragma unroll
        for (int ti = 0; ti < 4; ++ti)
#pragma unroll
            for (int r = 0; r < 4; ++r) {
                int row = rowBase + wm * 64 + ti * 16 + lq * 4 + r;
#pragma unroll
                for (int tj = 0; tj < 4; ++tj)
                    Out[(size_t)row * HS + colBase + wn * 64 + tj * 16 + lr] =
                        f2bf(acc[ti][tj][r]);
            }
    }
}

// ---- K4: dydx[k][n] = sum_j U[n][j]*d1[n][j]*W1[j][k]; also emit y (fp32 out) ----
__global__ __launch_bounds__(256) void k4_final(
    const float* __restrict__ x, const float* __restrict__ W1,
    const float* __restrict__ b1, const uint16_t* __restrict__ U,
    const float* __restrict__ yacc, const float* __restrict__ b3,
    float* __restrict__ out)
{
    const int n = (blockIdx.x * 256 + threadIdx.x) >> 6;
    const int lane = threadIdx.x & 63;
    float4 x0 = *(const float4*)(x + n * 8);
    float4 x1 = *(const float4*)(x + n * 8 + 4);
    float xf[8] = {x0.x, x0.y, x0.z, x0.w, x1.x, x1.y, x1.z, x1.w};
    float part[8] = {};
    for (int it = 0; it < 16; ++it) {
        int j = it * 64 + lane;
        float u = bf2f(U[(size_t)n * HS + j]);
        float4 w0 = *(const float4*)(W1 + j * 8);
        float4 w1 = *(const float4*)(W1 + j * 8 + 4);
        float wf[8] = {w0.x, w0.y, w0.z, w0.w, w1.x, w1.y, w1.z, w1.w};
        float s = b1[j];
#pragma unroll
        for (int k = 0; k < 8; ++k) s += xf[k] * wf[k];
        float z1 = tanhf(s);
        float c = u * (1.f - z1 * z1);
#pragma unroll
        for (int k = 0; k < 8; ++k) part[k] += c * wf[k];
    }
#pragma unroll
    for (int m = 1; m < 64; m <<= 1)
#pragma unroll
        for (int k = 0; k < 8; ++k) part[k] += __shfl_xor(part[k], m);
    if (lane == 0) {
        out[n] = yacc[n] + b3[0];
#pragma unroll
        for (int k = 0; k < 8; ++k) out[NXS + k * NXS + n] = part[k];
    }
}

extern "C" void kernel_launch(void* const* d_in, const int* in_sizes, int n_in,
                              void* d_out, int out_size, void* d_ws, size_t ws_size,
                              hipStream_t stream) {
    (void)in_sizes; (void)n_in; (void)out_size; (void)ws_size;
    const float* x  = (const float*)d_in[0];
    const float* W1 = (const float*)d_in[1];
    const float* b1 = (const float*)d_in[2];
    const float* W2 = (const float*)d_in[3];
    const float* b2 = (const float*)d_in[4];
    const float* W3 = (const float*)d_in[5];
    const float* b3 = (const float*)d_in[6];
    float* out = (float*)d_out;

    char* ws = (char*)d_ws;
    // ws layout (all scratch; re-poisoned to 0xAA before every launch):
    //   [0, 16MB)     Z1 bf16 (dead after GEMM1; aliased by U)
    //   [16MB, 32MB)  V bf16
    //   [32MB, 34MB)  W2c bf16 row-major
    //   [34MB, 36MB)  W2T bf16 transposed
    //   [36MB, +32KB) yacc fp32
    uint16_t* Z1  = (uint16_t*)(ws);
    uint16_t* U   = (uint16_t*)(ws);                               // alias of Z1
    uint16_t* V   = (uint16_t*)(ws + (size_t)16 * 1024 * 1024);
    uint16_t* W2c = (uint16_t*)(ws + (size_t)32 * 1024 * 1024);
    uint16_t* W2T = (uint16_t*)(ws + (size_t)34 * 1024 * 1024);
    float*    yac = (float*)   (ws + (size_t)36 * 1024 * 1024);

    hipMemsetAsync((void*)yac, 0, NXS * sizeof(float), stream);
    conv_w2<<<256, 256, 0, stream>>>(W2, W2c, W2T);
    k1_z1<<<NXS * HS / 256, 256, 0, stream>>>(x, W1, b1, Z1);
    gemm_k<0><<<dim3(NXS / 128, HS / 128), 256, 0, stream>>>(Z1, W2c, b2, W3, V, yac);
    gemm_k<1><<<dim3(NXS / 128, HS / 128), 256, 0, stream>>>(V, W2T, nullptr, nullptr, U, nullptr);
    k4_final<<<NXS / 4, 256, 0, stream>>>(x, W1, b1, U, yac, b3, out);
}

// Round 4
// 169.144 us; speedup vs baseline: 1.0017x; 1.0017x over previous
//
#include <hip/hip_runtime.h>
#include <stdint.h>

#define NXS 8192
#define HS  1024

typedef __attribute__((ext_vector_type(8))) short short8;
typedef __attribute__((ext_vector_type(4))) float f32x4;

__device__ __forceinline__ float bf2f(uint32_t b) {
    union { uint32_t u; float f; } c; c.u = b << 16; return c.f;
}
__device__ __forceinline__ uint16_t f2bf(float f) {
    union { float f; uint32_t u; } c; c.f = f;
    return (uint16_t)((c.u + 0x7fffu + ((c.u >> 16) & 1u)) >> 16);
}
__device__ __forceinline__ void async_cp16(const void* g, void* l) {
    __builtin_amdgcn_global_load_lds(
        (const __attribute__((address_space(1))) void*)g,
        (__attribute__((address_space(3))) void*)l,
        16, 0, 0);
}

// ---- K0: W2 (fp32) -> W2c (bf16 row-major) + W2T (bf16 transposed) ----
__global__ __launch_bounds__(256) void conv_w2(
    const float* __restrict__ W2, uint16_t* __restrict__ W2c,
    uint16_t* __restrict__ W2T)
{
    __shared__ uint16_t tile[64][65];
    const int bx = blockIdx.x & 15, by = blockIdx.x >> 4;
    const int tx = threadIdx.x & 63, ty = threadIdx.x >> 6;
#pragma unroll
    for (int rr = 0; rr < 64; rr += 4) {
        int r = ty + rr;
        uint16_t v = f2bf(W2[(size_t)(by * 64 + r) * HS + bx * 64 + tx]);
        W2c[(size_t)(by * 64 + r) * HS + bx * 64 + tx] = v;
        tile[r][tx] = v;
    }
    __syncthreads();
#pragma unroll
    for (int rr = 0; rr < 64; rr += 4)
        W2T[(size_t)(bx * 64 + ty + rr) * HS + by * 64 + tx] = tile[tx][ty + rr];
}

// ---- K1: Z1 = tanh(x @ W1^T + b1)  (fp32 in, bf16 out) ----
__global__ __launch_bounds__(256) void k1_z1(
    const float* __restrict__ x, const float* __restrict__ W1,
    const float* __restrict__ b1, uint16_t* __restrict__ Z1)
{
    const int idx = blockIdx.x * 256 + threadIdx.x;   // n*1024 + j
    const int n = idx >> 10, j = idx & 1023;
    float4 x0 = *(const float4*)(x + n * 8);
    float4 x1 = *(const float4*)(x + n * 8 + 4);
    float4 w0 = *(const float4*)(W1 + j * 8);
    float4 w1 = *(const float4*)(W1 + j * 8 + 4);
    float s = b1[j]
        + x0.x * w0.x + x0.y * w0.y + x0.z * w0.z + x0.w * w0.w
        + x1.x * w1.x + x1.y * w1.y + x1.z * w1.z + x1.w * w1.w;
    Z1[idx] = f2bf(tanhf(s));
}

// ---------------- GEMM (128x128 tile, mfma 16x16x32 bf16, LDS dbuf) ----------------
// MODE 0: C = A @ B^T (B row-major [N][K]); epilogue tanh -> V (bf16), y atomics
// MODE 1: plain bf16 store of C
template <int MODE>
__global__ __launch_bounds__(256) void gemm_k(
    const uint16_t* __restrict__ A, const uint16_t* __restrict__ B,
    const float* __restrict__ bias, const float* __restrict__ W3,
    uint16_t* __restrict__ Out, float* __restrict__ yacc)
{
    // two 8 KB buffers each for A and B tiles (128 rows x 32 K, bf16)
    __shared__ __attribute__((aligned(16))) uint16_t lsA[2][128 * 32];
    __shared__ __attribute__((aligned(16))) uint16_t lsB[2][128 * 32];
    const int t = threadIdx.x;
    const int wave = t >> 6, lane = t & 63;
    const int lq = lane >> 4, lr = lane & 15;
    const int wm = wave >> 1, wn = wave & 1;
    const int rowBase = blockIdx.x * 128;
    const int colBase = blockIdx.y * 128;
    const int sRow = t >> 2, sCol = (t & 3) * 8;

    const uint16_t* gA = A + (size_t)(rowBase + sRow) * HS + sCol;
    const uint16_t* gB = B + (size_t)(colBase + sRow) * HS + sCol;

    f32x4 acc[4][4] = {};

    // prologue: stage tile 0 into buffer 0
#pragma unroll
    for (int i = 0; i < 2; ++i) {
        async_cp16(gA + (size_t)i * 64 * HS, (char*)lsA[0] + i * 4096 + wave * 1024);
        async_cp16(gB + (size_t)i * 64 * HS, (char*)lsB[0] + i * 4096 + wave * 1024);
    }
    __syncthreads();

    int buf = 0;
    for (int k0 = 0; k0 < HS; k0 += 32, buf ^= 1) {
        // prefetch next tile into the other buffer; overlaps this tile's compute
        if (k0 + 32 < HS) {
#pragma unroll
            for (int i = 0; i < 2; ++i) {
                async_cp16(gA + (size_t)i * 64 * HS + (k0 + 32),
                           (char*)lsA[buf ^ 1] + i * 4096 + wave * 1024);
                async_cp16(gB + (size_t)i * 64 * HS + (k0 + 32),
                           (char*)lsB[buf ^ 1] + i * 4096 + wave * 1024);
            }
        }
        short8 af[4], bfr[4];
#pragma unroll
        for (int ti = 0; ti < 4; ++ti)
            af[ti] = *(const short8*)((const short*)lsA[buf] + (wm * 64 + ti * 16 + lr) * 32 + lq * 8);
#pragma unroll
        for (int tj = 0; tj < 4; ++tj)
            bfr[tj] = *(const short8*)((const short*)lsB[buf] + (wn * 64 + tj * 16 + lr) * 32 + lq * 8);
#pragma unroll
        for (int ti = 0; ti < 4; ++ti)
#pragma unroll
            for (int tj = 0; tj < 4; ++tj)
                acc[ti][tj] = __builtin_amdgcn_mfma_f32_16x16x32_bf16(
                    af[ti], bfr[tj], acc[ti][tj], 0, 0, 0);
        // one barrier per iter: drains prefetch (mostly landed) + guards buf reuse
        __syncthreads();
    }

    if (MODE == 0) {
        float cB[4], cW[4]; int cCol[4];
#pragma unroll
        for (int tj = 0; tj < 4; ++tj) {
            int col = colBase + wn * 64 + tj * 16 + lr;
            cCol[tj] = col;
            cB[tj] = bias[col];
            cW[tj] = W3[col];
        }
#pragma unroll
        for (int ti = 0; ti < 4; ++ti) {
#pragma unroll
            for (int r = 0; r < 4; ++r) {
                int row = rowBase + wm * 64 + ti * 16 + lq * 4 + r;
                float ys = 0.f;
#pragma unroll
                for (int tj = 0; tj < 4; ++tj) {
                    float z2 = tanhf(acc[ti][tj][r] + cB[tj]);
                    ys += z2 * cW[tj];
                    Out[(size_t)row * HS + cCol[tj]] = f2bf((1.f - z2 * z2) * cW[tj]);
                }
                ys += __shfl_xor(ys, 1); ys += __shfl_xor(ys, 2);
                ys += __shfl_xor(ys, 4); ys += __shfl_xor(ys, 8);
                if (lr == 0) atomicAdd(&yacc[row], ys);
            }
        }
    } else {
#pragma unroll
        for (int ti = 0; ti < 4; ++ti)
#pragma unroll
            for (int r = 0; r < 4; ++r) {
                int row = rowBase + wm * 64 + ti * 16 + lq * 4 + r;
#pragma unroll
                for (int tj = 0; tj < 4; ++tj)
                    Out[(size_t)row * HS + colBase + wn * 64 + tj * 16 + lr] =
                        f2bf(acc[ti][tj][r]);
            }
    }
}

// ---- K4: dydx[k][n] = sum_j U[n][j]*d1[n][j]*W1[j][k]; also emit y (fp32 out) ----
__global__ __launch_bounds__(256) void k4_final(
    const float* __restrict__ x, const float* __restrict__ W1,
    const float* __restrict__ b1, const uint16_t* __restrict__ U,
    const float* __restrict__ yacc, const float* __restrict__ b3,
    float* __restrict__ out)
{
    const int n = (blockIdx.x * 256 + threadIdx.x) >> 6;
    const int lane = threadIdx.x & 63;
    float4 x0 = *(const float4*)(x + n * 8);
    float4 x1 = *(const float4*)(x + n * 8 + 4);
    float xf[8] = {x0.x, x0.y, x0.z, x0.w, x1.x, x1.y, x1.z, x1.w};
    float part[8] = {};
    for (int it = 0; it < 16; ++it) {
        int j = it * 64 + lane;
        float u = bf2f(U[(size_t)n * HS + j]);
        float4 w0 = *(const float4*)(W1 + j * 8);
        float4 w1 = *(const float4*)(W1 + j * 8 + 4);
        float wf[8] = {w0.x, w0.y, w0.z, w0.w, w1.x, w1.y, w1.z, w1.w};
        float s = b1[j];
#pragma unroll
        for (int k = 0; k < 8; ++k) s += xf[k] * wf[k];
        float z1 = tanhf(s);
        float c = u * (1.f - z1 * z1);
#pragma unroll
        for (int k = 0; k < 8; ++k) part[k] += c * wf[k];
    }
#pragma unroll
    for (int m = 1; m < 64; m <<= 1)
#pragma unroll
        for (int k = 0; k < 8; ++k) part[k] += __shfl_xor(part[k], m);
    if (lane == 0) {
        out[n] = yacc[n] + b3[0];
#pragma unroll
        for (int k = 0; k < 8; ++k) out[NXS + k * NXS + n] = part[k];
    }
}

extern "C" void kernel_launch(void* const* d_in, const int* in_sizes, int n_in,
                              void* d_out, int out_size, void* d_ws, size_t ws_size,
                              hipStream_t stream) {
    (void)in_sizes; (void)n_in; (void)out_size; (void)ws_size;
    const float* x  = (const float*)d_in[0];
    const float* W1 = (const float*)d_in[1];
    const float* b1 = (const float*)d_in[2];
    const float* W2 = (const float*)d_in[3];
    const float* b2 = (const float*)d_in[4];
    const float* W3 = (const float*)d_in[5];
    const float* b3 = (const float*)d_in[6];
    float* out = (float*)d_out;

    char* ws = (char*)d_ws;
    // ws layout (all scratch; re-poisoned to 0xAA before every launch):
    //   [0, 16MB)     Z1 bf16 (dead after GEMM1; aliased by U)
    //   [16MB, 32MB)  V bf16
    //   [32MB, 34MB)  W2c bf16 row-major
    //   [34MB, 36MB)  W2T bf16 transposed
    //   [36MB, +32KB) yacc fp32
    uint16_t* Z1  = (uint16_t*)(ws);
    uint16_t* U   = (uint16_t*)(ws);                               // alias of Z1
    uint16_t* V   = (uint16_t*)(ws + (size_t)16 * 1024 * 1024);
    uint16_t* W2c = (uint16_t*)(ws + (size_t)32 * 1024 * 1024);
    uint16_t* W2T = (uint16_t*)(ws + (size_t)34 * 1024 * 1024);
    float*    yac = (float*)   (ws + (size_t)36 * 1024 * 1024);

    hipMemsetAsync((void*)yac, 0, NXS * sizeof(float), stream);
    conv_w2<<<256, 256, 0, stream>>>(W2, W2c, W2T);
    k1_z1<<<NXS * HS / 256, 256, 0, stream>>>(x, W1, b1, Z1);
    gemm_k<0><<<dim3(NXS / 128, HS / 128), 256, 0, stream>>>(Z1, W2c, b2, W3, V, yac);
    gemm_k<1><<<dim3(NXS / 128, HS / 128), 256, 0, stream>>>(V, W2T, nullptr, nullptr, U, nullptr);
    k4_final<<<NXS / 4, 256, 0, stream>>>(x, W1, b1, U, yac, b3, out);
}

// Round 5
// 150.735 us; speedup vs baseline: 1.1240x; 1.1221x over previous
//
#include <hip/hip_runtime.h>
#include <stdint.h>

#define NXS 8192
#define HS  1024

typedef __attribute__((ext_vector_type(8))) short short8;
typedef __attribute__((ext_vector_type(4))) float f32x4;

__device__ __forceinline__ float bf2f(uint32_t b) {
    union { uint32_t u; float f; } c; c.u = b << 16; return c.f;
}
__device__ __forceinline__ uint16_t f2bf(float f) {
    union { float f; uint32_t u; } c; c.f = f;
    return (uint16_t)((c.u + 0x7fffu + ((c.u >> 16) & 1u)) >> 16);
}
__device__ __forceinline__ void async_cp16(const void* g, void* l) {
    __builtin_amdgcn_global_load_lds(
        (const __attribute__((address_space(1))) void*)g,
        (__attribute__((address_space(3))) void*)l,
        16, 0, 0);
}

// ---- K0: W2 fp32 -> W2c (bf16 row-major) + W2T (bf16 transposed); zero yacc ----
__global__ __launch_bounds__(256) void conv_w2(
    const float* __restrict__ W2, uint16_t* __restrict__ W2c,
    uint16_t* __restrict__ W2T, float* __restrict__ yacc)
{
    __shared__ uint16_t tile[64][65];
    const int gid = blockIdx.x * 256 + threadIdx.x;
    if (gid < NXS) yacc[gid] = 0.f;
    const int bx = blockIdx.x & 15, by = blockIdx.x >> 4;
    const int tx = threadIdx.x & 63, ty = threadIdx.x >> 6;
#pragma unroll
    for (int rr = 0; rr < 64; rr += 4) {
        int r = ty + rr;
        uint16_t v = f2bf(W2[(size_t)(by * 64 + r) * HS + bx * 64 + tx]);
        W2c[(size_t)(by * 64 + r) * HS + bx * 64 + tx] = v;
        tile[r][tx] = v;
    }
    __syncthreads();
#pragma unroll
    for (int rr = 0; rr < 64; rr += 4)
        W2T[(size_t)(bx * 64 + ty + rr) * HS + by * 64 + tx] = tile[tx][ty + rr];
}

// ---- K1: Z1 = tanh(x @ W1^T + b1)  (fp32 in, bf16 out) ----
__global__ __launch_bounds__(256) void k1_z1(
    const float* __restrict__ x, const float* __restrict__ W1,
    const float* __restrict__ b1, uint16_t* __restrict__ Z1)
{
    const int idx = blockIdx.x * 256 + threadIdx.x;   // n*1024 + j
    const int n = idx >> 10, j = idx & 1023;
    float4 x0 = *(const float4*)(x + n * 8);
    float4 x1 = *(const float4*)(x + n * 8 + 4);
    float4 w0 = *(const float4*)(W1 + j * 8);
    float4 w1 = *(const float4*)(W1 + j * 8 + 4);
    float s = b1[j]
        + x0.x * w0.x + x0.y * w0.y + x0.z * w0.z + x0.w * w0.w
        + x1.x * w1.x + x1.y * w1.y + x1.z * w1.z + x1.w * w1.w;
    Z1[idx] = f2bf(tanhf(s));
}

// -------- GEMM: 128x128 tile, 8 waves (512 thr), BK=64, swizzled LDS --------
// MODE 0: C = A @ B^T (B row-major [N][K]); epilogue tanh -> V (bf16), y atomics
// MODE 1: plain bf16 store of C
// LDS element (r, kq*8..kq*8+7) lives at row r, 16B-slot (kq ^ (r&7)).
template <int MODE>
__global__ __launch_bounds__(512) void gemm_k(
    const uint16_t* __restrict__ A, const uint16_t* __restrict__ B,
    const float* __restrict__ bias, const float* __restrict__ W3,
    uint16_t* __restrict__ Out, float* __restrict__ yacc)
{
    __shared__ __attribute__((aligned(16))) uint16_t lsA[2][128 * 64];
    __shared__ __attribute__((aligned(16))) uint16_t lsB[2][128 * 64];
    const int t = threadIdx.x;
    const int wave = t >> 6, lane = t & 63;
    const int lq = lane >> 4, lr = lane & 15;
    const int wm = wave >> 1, wn = wave & 1;         // wm 0..3, wn 0..1
    const int rowBase = blockIdx.x * 128;
    const int colBase = blockIdx.y * 128;

    // staging: 1024 16B-segs per matrix per tile; thread t handles s0=t, s1=512+t
    const int s0 = t, s1 = 512 + t;
    const int r0 = s0 >> 3, q0 = (s0 & 7) ^ (r0 & 7);
    const int r1 = s1 >> 3, q1 = (s1 & 7) ^ (r1 & 7);
    const uint16_t* gA0 = A + (size_t)(rowBase + r0) * HS + q0 * 8;
    const uint16_t* gA1 = A + (size_t)(rowBase + r1) * HS + q1 * 8;
    const uint16_t* gB0 = B + (size_t)(colBase + r0) * HS + q0 * 8;
    const uint16_t* gB1 = B + (size_t)(colBase + r1) * HS + q1 * 8;

    f32x4 acc[2][4] = {};

    async_cp16(gA0, (char*)lsA[0] + s0 * 16);
    async_cp16(gA1, (char*)lsA[0] + s1 * 16);
    async_cp16(gB0, (char*)lsB[0] + s0 * 16);
    async_cp16(gB1, (char*)lsB[0] + s1 * 16);
    __syncthreads();

    int buf = 0;
    for (int k0 = 0; k0 < HS; k0 += 64, buf ^= 1) {
        if (k0 + 64 < HS) {
            const int ko = k0 + 64;
            async_cp16(gA0 + ko, (char*)lsA[buf ^ 1] + s0 * 16);
            async_cp16(gA1 + ko, (char*)lsA[buf ^ 1] + s1 * 16);
            async_cp16(gB0 + ko, (char*)lsB[buf ^ 1] + s0 * 16);
            async_cp16(gB1 + ko, (char*)lsB[buf ^ 1] + s1 * 16);
        }
#pragma unroll
        for (int kk = 0; kk < 64; kk += 32) {
            const int kq = (kk >> 3) + lq;           // 16B-slot index pre-swizzle
            short8 af[2], bfr[4];
#pragma unroll
            for (int ti = 0; ti < 2; ++ti) {
                int ar = wm * 32 + ti * 16 + lr;
                af[ti] = *(const short8*)((const short*)lsA[buf]
                          + ar * 64 + ((kq ^ (ar & 7)) << 3));
            }
#pragma unroll
            for (int tj = 0; tj < 4; ++tj) {
                int br = wn * 64 + tj * 16 + lr;
                bfr[tj] = *(const short8*)((const short*)lsB[buf]
                          + br * 64 + ((kq ^ (br & 7)) << 3));
            }
#pragma unroll
            for (int ti = 0; ti < 2; ++ti)
#pragma unroll
                for (int tj = 0; tj < 4; ++tj)
                    acc[ti][tj] = __builtin_amdgcn_mfma_f32_16x16x32_bf16(
                        af[ti], bfr[tj], acc[ti][tj], 0, 0, 0);
        }
        __syncthreads();
    }

    if (MODE == 0) {
        float cB[4], cW[4]; int cCol[4];
#pragma unroll
        for (int tj = 0; tj < 4; ++tj) {
            int col = colBase + wn * 64 + tj * 16 + lr;
            cCol[tj] = col;
            cB[tj] = bias[col];
            cW[tj] = W3[col];
        }
#pragma unroll
        for (int ti = 0; ti < 2; ++ti) {
#pragma unroll
            for (int r = 0; r < 4; ++r) {
                int row = rowBase + wm * 32 + ti * 16 + lq * 4 + r;
                float ys = 0.f;
#pragma unroll
                for (int tj = 0; tj < 4; ++tj) {
                    float z2 = tanhf(acc[ti][tj][r] + cB[tj]);
                    ys += z2 * cW[tj];
                    Out[(size_t)row * HS + cCol[tj]] = f2bf((1.f - z2 * z2) * cW[tj]);
                }
                ys += __shfl_xor(ys, 1); ys += __shfl_xor(ys, 2);
                ys += __shfl_xor(ys, 4); ys += __shfl_xor(ys, 8);
                if (lr == 0) atomicAdd(&yacc[row], ys);
            }
        }
    } else {
#pragma unroll
        for (int ti = 0; ti < 2; ++ti)
#pragma unroll
            for (int r = 0; r < 4; ++r) {
                int row = rowBase + wm * 32 + ti * 16 + lq * 4 + r;
#pragma unroll
                for (int tj = 0; tj < 4; ++tj)
                    Out[(size_t)row * HS + colBase + wn * 64 + tj * 16 + lr] =
                        f2bf(acc[ti][tj][r]);
            }
    }
}

// ---- K4: dydx[k][n] = sum_j U[n][j]*d1[n][j]*W1[j][k]; also emit y (fp32 out) ----
__global__ __launch_bounds__(256) void k4_final(
    const float* __restrict__ x, const float* __restrict__ W1,
    const float* __restrict__ b1, const uint16_t* __restrict__ U,
    const float* __restrict__ yacc, const float* __restrict__ b3,
    float* __restrict__ out)
{
    const int n = (blockIdx.x * 256 + threadIdx.x) >> 6;
    const int lane = threadIdx.x & 63;
    float4 x0 = *(const float4*)(x + n * 8);
    float4 x1 = *(const float4*)(x + n * 8 + 4);
    float xf[8] = {x0.x, x0.y, x0.z, x0.w, x1.x, x1.y, x1.z, x1.w};
    float part[8] = {};
    for (int it = 0; it < 16; ++it) {
        int j = it * 64 + lane;
        float u = bf2f(U[(size_t)n * HS + j]);
        float4 w0 = *(const float4*)(W1 + j * 8);
        float4 w1 = *(const float4*)(W1 + j * 8 + 4);
        float wf[8] = {w0.x, w0.y, w0.z, w0.w, w1.x, w1.y, w1.z, w1.w};
        float s = b1[j];
#pragma unroll
        for (int k = 0; k < 8; ++k) s += xf[k] * wf[k];
        float z1 = tanhf(s);
        float c = u * (1.f - z1 * z1);
#pragma unroll
        for (int k = 0; k < 8; ++k) part[k] += c * wf[k];
    }
#pragma unroll
    for (int m = 1; m < 64; m <<= 1)
#pragma unroll
        for (int k = 0; k < 8; ++k) part[k] += __shfl_xor(part[k], m);
    if (lane == 0) {
        out[n] = yacc[n] + b3[0];
#pragma unroll
        for (int k = 0; k < 8; ++k) out[NXS + k * NXS + n] = part[k];
    }
}

extern "C" void kernel_launch(void* const* d_in, const int* in_sizes, int n_in,
                              void* d_out, int out_size, void* d_ws, size_t ws_size,
                              hipStream_t stream) {
    (void)in_sizes; (void)n_in; (void)out_size; (void)ws_size;
    const float* x  = (const float*)d_in[0];
    const float* W1 = (const float*)d_in[1];
    const float* b1 = (const float*)d_in[2];
    const float* W2 = (const float*)d_in[3];
    const float* b2 = (const float*)d_in[4];
    const float* W3 = (const float*)d_in[5];
    const float* b3 = (const float*)d_in[6];
    float* out = (float*)d_out;

    char* ws = (char*)d_ws;
    // ws layout:
    //   [0, 16MB)     Z1 bf16 (dead after GEMM1; aliased by U)
    //   [16MB, 32MB)  V bf16
    //   [32MB, 34MB)  W2c bf16 row-major
    //   [34MB, 36MB)  W2T bf16 transposed
    //   [36MB, +32KB) yacc fp32 (zeroed in conv_w2)
    uint16_t* Z1  = (uint16_t*)(ws);
    uint16_t* U   = (uint16_t*)(ws);                               // alias of Z1
    uint16_t* V   = (uint16_t*)(ws + (size_t)16 * 1024 * 1024);
    uint16_t* W2c = (uint16_t*)(ws + (size_t)32 * 1024 * 1024);
    uint16_t* W2T = (uint16_t*)(ws + (size_t)34 * 1024 * 1024);
    float*    yac = (float*)   (ws + (size_t)36 * 1024 * 1024);

    conv_w2<<<256, 256, 0, stream>>>(W2, W2c, W2T, yac);
    k1_z1<<<NXS * HS / 256, 256, 0, stream>>>(x, W1, b1, Z1);
    gemm_k<0><<<dim3(NXS / 128, HS / 128), 512, 0, stream>>>(Z1, W2c, b2, W3, V, yac);
    gemm_k<1><<<dim3(NXS / 128, HS / 128), 512, 0, stream>>>(V, W2T, nullptr, nullptr, U, nullptr);
    k4_final<<<NXS / 4, 256, 0, stream>>>(x, W1, b1, U, yac, b3, out);
}